// Round 1
// baseline (291.353 us; speedup 1.0000x reference)
//
#include <hip/hip_runtime.h>
#include <stdint.h>

// SoftmaxAttention: x[2,2048,2048] f32, w_qkv[6144,2048] f32, w_out[2048,2048] f32
// out[2,2048,2048] f32.  All matmul-shaped compute via bf16 MFMA 16x16x32.

typedef __attribute__((ext_vector_type(8))) short bf16x8;
typedef __attribute__((ext_vector_type(8))) unsigned short u16x8;
typedef __attribute__((ext_vector_type(4))) unsigned short u16x4;
typedef __attribute__((ext_vector_type(4))) float f32x4;

#define MFMA16(a, b, c) __builtin_amdgcn_mfma_f32_16x16x32_bf16((a), (b), (c), 0, 0, 0)

__device__ __forceinline__ unsigned short f2bf(float f) {
  union { float f; uint32_t u; } v; v.f = f;
  uint32_t r = v.u + 0x7FFFu + ((v.u >> 16) & 1u);  // RNE
  return (unsigned short)(r >> 16);
}

__device__ __forceinline__ void gld_lds16(const unsigned short* g, unsigned short* lds) {
  __builtin_amdgcn_global_load_lds(
      (const __attribute__((address_space(1))) void*)g,
      (__attribute__((address_space(3))) void*)lds, 16, 0, 0);
}

// ---------------------------------------------------------------- cvt f32->bf16
__global__ __launch_bounds__(256) void cvt_bf16(const float* __restrict__ in,
                                                unsigned short* __restrict__ out, int n8) {
  int stride = gridDim.x * blockDim.x;
  for (int i = blockIdx.x * blockDim.x + threadIdx.x; i < n8; i += stride) {
    float4 a = reinterpret_cast<const float4*>(in)[i * 2];
    float4 b = reinterpret_cast<const float4*>(in)[i * 2 + 1];
    u16x8 o;
    o[0] = f2bf(a.x); o[1] = f2bf(a.y); o[2] = f2bf(a.z); o[3] = f2bf(a.w);
    o[4] = f2bf(b.x); o[5] = f2bf(b.y); o[6] = f2bf(b.z); o[7] = f2bf(b.w);
    reinterpret_cast<u16x8*>(out)[i] = o;
  }
}

// --------------------------------------------------- 128x128 bf16 GEMM core (B^T)
// C[m][n] = sum_k A[m][k] * Bt[n][k].  256 threads, 4 waves (2x2 of 64x64).
// LDS tiles [128][32] bf16, granule-swizzled g ^= (row>>1)&3 on both stage & read.
__device__ __forceinline__ void gemm128_core(const unsigned short* __restrict__ A,
                                             const unsigned short* __restrict__ Bt,
                                             int K, int brow, int bcol,
                                             unsigned short* lds_a, unsigned short* lds_b,
                                             f32x4 acc[4][4]) {
  const int tid = threadIdx.x;
  const int l   = tid & 63;
  const int w   = tid >> 6;
  const int wr  = (w >> 1) << 6;
  const int wc  = (w & 1) << 6;

  const int srow = tid >> 2;                       // staging row within 64-row chunk
  const int sswz = (tid & 3) ^ ((srow >> 1) & 3);  // swizzled 16B granule
  const unsigned short* gA0 = A  + (size_t)(brow + srow) * K + 8 * sswz;
  const unsigned short* gA1 = gA0 + (size_t)64 * K;
  const unsigned short* gB0 = Bt + (size_t)(bcol + srow) * K + 8 * sswz;
  const unsigned short* gB1 = gB0 + (size_t)64 * K;

  unsigned short* la0 = lds_a + tid * 8;
  unsigned short* la1 = lds_a + (256 + tid) * 8;
  unsigned short* lb0 = lds_b + tid * 8;
  unsigned short* lb1 = lds_b + (256 + tid) * 8;

  const int fm    = l & 15;
  const int fswz8 = 8 * ((l >> 4) ^ ((fm >> 1) & 3));

  for (int k0 = 0; k0 < K; k0 += 32) {
    gld_lds16(gA0, la0);
    gld_lds16(gA1, la1);
    gld_lds16(gB0, lb0);
    gld_lds16(gB1, lb1);
    gA0 += 32; gA1 += 32; gB0 += 32; gB1 += 32;
    __syncthreads();  // drains vmcnt(0): staged data visible
    bf16x8 af[4], bfv[4];
#pragma unroll
    for (int i = 0; i < 4; i++)
      af[i] = *(const bf16x8*)&lds_a[(wr + i * 16 + fm) * 32 + fswz8];
#pragma unroll
    for (int j = 0; j < 4; j++)
      bfv[j] = *(const bf16x8*)&lds_b[(wc + j * 16 + fm) * 32 + fswz8];
#pragma unroll
    for (int i = 0; i < 4; i++)
#pragma unroll
      for (int j = 0; j < 4; j++)
        acc[i][j] = MFMA16(af[i], bfv[j], acc[i][j]);
    __syncthreads();
  }
}

// --------------------------------------------------------------- QKV projection
// A = xb [4096,2048], Bt = wqkvb [6144,2048].  Epilogue: Q,K -> [BH,T,128],
// V -> transposed [BH,128,T] so attention PV reads are k-contiguous.
__global__ __launch_bounds__(256) void gemm_qkv(const unsigned short* __restrict__ xb,
                                                const unsigned short* __restrict__ wqb,
                                                unsigned short* __restrict__ Qb,
                                                unsigned short* __restrict__ Kb,
                                                unsigned short* __restrict__ Vtb) {
  __shared__ alignas(16) unsigned short lds_a[128 * 32];
  __shared__ alignas(16) unsigned short lds_b[128 * 32];
  f32x4 acc[4][4];
#pragma unroll
  for (int i = 0; i < 4; i++)
#pragma unroll
    for (int j = 0; j < 4; j++) acc[i][j] = (f32x4){0.f, 0.f, 0.f, 0.f};

  const int brow = blockIdx.y << 7;
  const int bcol = blockIdx.x << 7;
  gemm128_core(xb, wqb, 2048, brow, bcol, lds_a, lds_b, acc);

  const int l = threadIdx.x & 63;
  const int w = threadIdx.x >> 6;
  const int wr = (w >> 1) << 6, wc = (w & 1) << 6;
  const int which = bcol >> 11;                         // 0=Q 1=K 2=V (block-uniform)
  const int bh = ((brow >> 11) << 4) | ((bcol >> 7) & 15);
  const int tbase = (brow & 2047) + wr + ((l >> 4) << 2);

#pragma unroll
  for (int i = 0; i < 4; i++) {
    const int t0 = tbase + i * 16;
#pragma unroll
    for (int j = 0; j < 4; j++) {
      const int d = wc + j * 16 + (l & 15);
      if (which == 2) {
        u16x4 pk;
#pragma unroll
        for (int r = 0; r < 4; r++) pk[r] = f2bf(acc[i][j][r]);
        *reinterpret_cast<u16x4*>(&Vtb[((size_t)bh * 128 + d) * 2048 + t0]) = pk;
      } else {
        unsigned short* dst = (which == 0 ? Qb : Kb) + ((size_t)bh * 2048 + t0) * 128 + d;
#pragma unroll
        for (int r = 0; r < 4; r++) dst[(size_t)r * 128] = f2bf(acc[i][j][r]);
      }
    }
  }
}

// -------------------------------------------------------------- output projection
__global__ __launch_bounds__(256) void gemm_out(const unsigned short* __restrict__ yb,
                                                const unsigned short* __restrict__ wob,
                                                float* __restrict__ out) {
  __shared__ alignas(16) unsigned short lds_a[128 * 32];
  __shared__ alignas(16) unsigned short lds_b[128 * 32];
  f32x4 acc[4][4];
#pragma unroll
  for (int i = 0; i < 4; i++)
#pragma unroll
    for (int j = 0; j < 4; j++) acc[i][j] = (f32x4){0.f, 0.f, 0.f, 0.f};

  const int brow = blockIdx.y << 7;
  const int bcol = blockIdx.x << 7;
  gemm128_core(yb, wob, 2048, brow, bcol, lds_a, lds_b, acc);

  const int l = threadIdx.x & 63;
  const int w = threadIdx.x >> 6;
  const int wr = (w >> 1) << 6, wc = (w & 1) << 6;
#pragma unroll
  for (int i = 0; i < 4; i++) {
    const int m0 = brow + wr + i * 16 + ((l >> 4) << 2);
#pragma unroll
    for (int j = 0; j < 4; j++) {
      const int n = bcol + wc + j * 16 + (l & 15);
#pragma unroll
      for (int r = 0; r < 4; r++) out[(size_t)(m0 + r) * 2048 + n] = acc[i][j][r];
    }
  }
}

// ------------------------------------------------------------------ flash attn
// Per block: one bh, two 64-row causal q-half-tiles (j and 31-j) => exactly 33
// kv-steps per block, perfect balance.  4 waves x 16 q-rows.  KV tile = 64.
// K LDS [64][128] swizzled (g16 ^ row&7); V^T LDS [128][64] swizzled (g8 ^ d&7).
__global__ __launch_bounds__(256) void attn_kernel(const unsigned short* __restrict__ Qb,
                                                   const unsigned short* __restrict__ Kb,
                                                   const unsigned short* __restrict__ Vtb,
                                                   unsigned short* __restrict__ Yb) {
  __shared__ alignas(16) unsigned short lds_k[64 * 128];
  __shared__ alignas(16) unsigned short lds_v[128 * 64];
  __shared__ alignas(16) unsigned short p_lds[4][16 * 64];

  const int tid = threadIdx.x;
  const int l = tid & 63;
  const int w = tid >> 6;
  const int bh = blockIdx.y;
  const int b = bh >> 4, h = bh & 15;
  const float SC = 0.12752585f;  // log2(e)/sqrt(128)

  const unsigned short* Qg = Qb + (size_t)bh * 2048 * 128;
  const unsigned short* Kg = Kb + (size_t)bh * 2048 * 128;
  const unsigned short* Vg = Vtb + (size_t)bh * 128 * 2048;

  for (int ph = 0; ph < 2; ph++) {
    const int h64 = (ph == 0) ? (int)blockIdx.x : (31 - (int)blockIdx.x);
    const int q0 = h64 << 6;
    const int qw0 = q0 + (w << 4);

    // Q fragments in registers (A-operand: m = l&15, k = ds*32 + 8*(l>>4))
    bf16x8 qf[4];
#pragma unroll
    for (int ds = 0; ds < 4; ds++)
      qf[ds] = *(const bf16x8*)&Qg[(size_t)(qw0 + (l & 15)) * 128 + ds * 32 + 8 * (l >> 4)];

    f32x4 yacc[8];
#pragma unroll
    for (int dt = 0; dt < 8; dt++) yacc[dt] = (f32x4){0.f, 0.f, 0.f, 0.f};
    float mrow[4], lrow[4];
#pragma unroll
    for (int r = 0; r < 4; r++) { mrow[r] = -1e30f; lrow[r] = 0.f; }

    const int nkv = h64 + 1;
    for (int t = 0; t < nkv; t++) {
      const int kv0 = t << 6;
      // stage K [64][128]: 16 granules/row, source pre-swizzled (rule #21)
#pragma unroll
      for (int c = 0; c < 4; c++) {
        int s = c * 256 + tid;
        int row = s >> 4, g = s & 15;
        gld_lds16(&Kg[(size_t)(kv0 + row) * 128 + 8 * (g ^ (row & 7))], &lds_k[s * 8]);
      }
      // stage V^T [128][64]: 8 granules/row
#pragma unroll
      for (int c = 0; c < 4; c++) {
        int s = c * 256 + tid;
        int row = s >> 3, g = s & 7;
        gld_lds16(&Vg[(size_t)row * 2048 + kv0 + 8 * (g ^ (row & 7))], &lds_v[s * 8]);
      }
      __syncthreads();

      if (kv0 <= qw0 + 15) {  // wave has at least one unmasked row
        // S = Q K^T : 16 MFMA
        f32x4 sfr[4];
#pragma unroll
        for (int kt = 0; kt < 4; kt++) {
          const int kr = kt * 16 + (l & 15);
          f32x4 s4 = (f32x4){0.f, 0.f, 0.f, 0.f};
#pragma unroll
          for (int ds = 0; ds < 4; ds++) {
            bf16x8 kfr = *(const bf16x8*)&lds_k[kr * 128 + 8 * (((ds << 2) + (l >> 4)) ^ (kr & 7))];
            s4 = MFMA16(qf[ds], kfr, s4);
          }
          sfr[kt] = s4;
        }
        const bool need_mask = (kv0 + 63 > qw0);
#pragma unroll
        for (int kt = 0; kt < 4; kt++)
#pragma unroll
          for (int r = 0; r < 4; r++) {
            float sv = sfr[kt][r] * SC;
            if (need_mask) {
              int qa = qw0 + ((l >> 4) << 2) + r;
              int ka = kv0 + kt * 16 + (l & 15);
              sv = (ka > qa) ? -1e30f : sv;
            }
            sfr[kt][r] = sv;
          }
        // online softmax (log2 domain); rows live at (l>>4)*4 + r, cols on l&15
        float rmax, f[4], rsum[4];
#pragma unroll
        for (int r = 0; r < 4; r++) {
          rmax = fmaxf(fmaxf(sfr[0][r], sfr[1][r]), fmaxf(sfr[2][r], sfr[3][r]));
          rmax = fmaxf(rmax, __shfl_xor(rmax, 1));
          rmax = fmaxf(rmax, __shfl_xor(rmax, 2));
          rmax = fmaxf(rmax, __shfl_xor(rmax, 4));
          rmax = fmaxf(rmax, __shfl_xor(rmax, 8));
          float mn = fmaxf(mrow[r], rmax);
          f[r] = exp2f(mrow[r] - mn);
          mrow[r] = mn;
          rsum[r] = 0.f;
        }
        // P = exp2(S - m), stash bf16 into per-wave swizzled LDS
#pragma unroll
        for (int kt = 0; kt < 4; kt++)
#pragma unroll
          for (int r = 0; r < 4; r++) {
            float p = exp2f(sfr[kt][r] - mrow[r]);
            rsum[r] += p;
            int row = ((l >> 4) << 2) + r;
            int k = kt * 16 + (l & 15);
            p_lds[w][row * 64 + (((k >> 3) ^ (row & 7)) << 3) + (k & 7)] = f2bf(p);
          }
#pragma unroll
        for (int r = 0; r < 4; r++) {
          float s = rsum[r];
          s += __shfl_xor(s, 1);
          s += __shfl_xor(s, 2);
          s += __shfl_xor(s, 4);
          s += __shfl_xor(s, 8);
          lrow[r] = lrow[r] * f[r] + s;
        }
#pragma unroll
        for (int dt = 0; dt < 8; dt++)
#pragma unroll
          for (int r = 0; r < 4; r++) yacc[dt][r] *= f[r];

        // cross-lane LDS write->read fence (same wave)
        asm volatile("s_waitcnt lgkmcnt(0)" ::: "memory");
        __builtin_amdgcn_sched_barrier(0);

        // PV: 16 MFMA.  A = P (m = l&15, k = ks*32+8*(l>>4)), B = V from V^T LDS
#pragma unroll
        for (int ks = 0; ks < 2; ks++) {
          const int prow = l & 15;
          bf16x8 pa = *(const bf16x8*)&p_lds[w][prow * 64 + ((((ks << 2) + (l >> 4)) ^ (prow & 7)) << 3)];
#pragma unroll
          for (int dt = 0; dt < 8; dt++) {
            const int d = dt * 16 + (l & 15);
            bf16x8 vb = *(const bf16x8*)&lds_v[d * 64 + ((((ks << 2) + (l >> 4)) ^ (d & 7)) << 3)];
            yacc[dt] = MFMA16(pa, vb, yacc[dt]);
          }
        }
      }
      __syncthreads();
    }
    // epilogue: y = acc / l, bf16 into [B,T,C] (C index = h*128 + d)
#pragma unroll
    for (int dt = 0; dt < 8; dt++)
#pragma unroll
      for (int r = 0; r < 4; r++) {
        int qa = qw0 + ((l >> 4) << 2) + r;
        Yb[((size_t)(b * 2048 + qa)) * 2048 + h * 128 + dt * 16 + (l & 15)] =
            f2bf(yacc[dt][r] / lrow[r]);
      }
  }
}

// ---------------------------------------------------------------------- launch
extern "C" void kernel_launch(void* const* d_in, const int* in_sizes, int n_in,
                              void* d_out, int out_size, void* d_ws, size_t ws_size,
                              hipStream_t stream) {
  const float* x    = (const float*)d_in[0];
  const float* wqkv = (const float*)d_in[1];
  const float* wout = (const float*)d_in[2];
  float* out = (float*)d_out;

  // workspace layout (bf16 elements); total = 58,720,256 elems = 117.4 MB
  unsigned short* ws  = (unsigned short*)d_ws;
  unsigned short* xb  = ws;                        // 4096*2048
  unsigned short* wqb = xb + (size_t)8388608;      // 6144*2048
  unsigned short* wob = wqb + (size_t)12582912;    // 2048*2048
  unsigned short* Qb  = wob + (size_t)4194304;     // [32,2048,128]
  unsigned short* Kb  = Qb + (size_t)8388608;      // [32,2048,128]
  unsigned short* Vtb = Kb + (size_t)8388608;      // [32,128,2048] (transposed)
  unsigned short* Yb  = Vtb + (size_t)8388608;     // [4096,2048]

  cvt_bf16<<<1024, 256, 0, stream>>>(x, xb, 8388608 / 8);
  cvt_bf16<<<1024, 256, 0, stream>>>(wqkv, wqb, 12582912 / 8);
  cvt_bf16<<<512, 256, 0, stream>>>(wout, wob, 4194304 / 8);
  gemm_qkv<<<dim3(48, 32), 256, 0, stream>>>(xb, wqb, Qb, Kb, Vtb);
  attn_kernel<<<dim3(16, 32), 256, 0, stream>>>(Qb, Kb, Vtb, Yb);
  gemm_out<<<dim3(16, 32), 256, 0, stream>>>(Yb, wob, out);
}